// Round 1
// baseline (549.039 us; speedup 1.0000x reference)
//
#include <hip/hip_runtime.h>
#include <stdint.h>

#define DD 1024
#define BATCH 32768

typedef unsigned short u16;
typedef __attribute__((ext_vector_type(8))) __bf16 bf16x8;
typedef __attribute__((ext_vector_type(4))) float f32x4;
typedef __attribute__((ext_vector_type(4))) unsigned int u32x4;

__device__ __forceinline__ u16 f2bf(float x) {
  unsigned int u = __builtin_bit_cast(unsigned int, x);
  u = u + 0x7FFFu + ((u >> 16) & 1u);   // round-to-nearest-even
  return (u16)(u >> 16);
}

__global__ void cvt_f32_to_bf16(const float4* __restrict__ src,
                                ushort4* __restrict__ dst, int n4) {
  int i = blockIdx.x * blockDim.x + threadIdx.x;
  int stride = gridDim.x * blockDim.x;
  for (; i < n4; i += stride) {
    float4 v = src[i];
    ushort4 o;
    o.x = f2bf(v.x); o.y = f2bf(v.y); o.z = f2bf(v.z); o.w = f2bf(v.w);
    dst[i] = o;
  }
}

// ---------------- fused GRU GEMM ----------------
// LDS layout (u16 units): A_in[128][64], A_h[128][64], W[g][64][64] g=0..5
// All tiles row-major, 64 bf16 (=128 B = 8x 16B slots) per row.
// Swizzle: 16B slot s of row R holds natural slot (s ^ (R&7)).
#define A_IN_U 0
#define A_H_U  8192
#define W_U(g) (16384 + (g) * 4096)

__device__ __forceinline__ bf16x8 ld8(const u16* p) {
  u32x4 v = *reinterpret_cast<const u32x4*>(p);
  return __builtin_bit_cast(bf16x8, v);
}

__device__ __forceinline__ f32x4 mfma16(bf16x8 a, bf16x8 b, f32x4 c) {
  return __builtin_amdgcn_mfma_f32_16x16x32_bf16(a, b, c, 0, 0, 0);
}

// Stage one 1024B chunk (8 rows x 128B) of a tile via global_load_lds.
// grow points at &G[tile_row0 + chunk*8][kcol]; ldsdst is wave-uniform.
// Global source is pre-swizzled per-lane: lane l -> row (l>>3), slot (l&7),
// fetching natural k-slot ((l&7) ^ (l>>3)) so linear LDS holds swizzled data.
__device__ __forceinline__ void stage_chunk(const u16* grow, u16* ldsdst) {
  int l = threadIdx.x & 63;
  int r = l >> 3;
  int s = l & 7;
  const u16* src = grow + r * DD + ((s ^ r) << 3);
  __builtin_amdgcn_global_load_lds(
      (const __attribute__((address_space(1))) void*)src,
      (__attribute__((address_space(3))) void*)ldsdst, 16, 0, 0);
}

__global__ __launch_bounds__(256, 2) void gru_fused(
    const u16* __restrict__ ain, const u16* __restrict__ ah,
    const u16* __restrict__ wall, const float* __restrict__ hidf,
    const float* __restrict__ b_ir, const float* __restrict__ b_hr,
    const float* __restrict__ b_iz, const float* __restrict__ b_hz,
    const float* __restrict__ b_in, const float* __restrict__ b_hn,
    float* __restrict__ out) {
  __shared__ __align__(16) u16 lds[40960];  // 80 KB -> 2 blocks/CU

  int bid = blockIdx.x;
  // XCD-bijective swizzle (4096 % 8 == 0), mb-fastest: each XCD keeps its
  // 2 weight column-slices L2-resident; A panels re-read from L3.
  int wg = ((bid & 7) << 9) | (bid >> 3);
  int nb = wg >> 8;    // 0..15   (64-col slice of D)
  int mb = wg & 255;   // 0..255  (128-row slice of batch)

  int tid = threadIdx.x;
  int wid = tid >> 6;
  int lane = tid & 63;
  int r15 = lane & 15;
  int kb = lane >> 4;
  int wm = wid >> 1;   // 2x2 wave grid, wave tile 64x32
  int wn = wid & 1;

  const f32x4 zero = {0.f, 0.f, 0.f, 0.f};
  f32x4 acc_r[4][2], acc_z[4][2], acc_n[4][2], acc_hn[4][2];
#pragma unroll
  for (int i = 0; i < 4; ++i)
#pragma unroll
    for (int j = 0; j < 2; ++j) {
      acc_r[i][j] = zero; acc_z[i][j] = zero;
      acc_n[i][j] = zero; acc_hn[i][j] = zero;
    }

  const u16* ain_t = ain + ((size_t)(mb * 128) << 10);
  const u16* ah_t  = ah  + ((size_t)(mb * 128) << 10);
  const u16* w_t   = wall + ((size_t)(nb * 64) << 10);

  for (int kt = 0; kt < 16; ++kt) {
    int kcol = kt << 6;
    __syncthreads();  // previous iter's compute done before overwrite
    // A tiles: 16 chunks each, 4 per wave
#pragma unroll
    for (int j = 0; j < 4; ++j) {
      int c = (j << 2) | wid;
      stage_chunk(ain_t + ((size_t)c << 13) + kcol, &lds[A_IN_U + c * 512]);
      stage_chunk(ah_t  + ((size_t)c << 13) + kcol, &lds[A_H_U  + c * 512]);
    }
    // W tiles: 8 chunks each, 2 per wave
#pragma unroll
    for (int g = 0; g < 6; ++g) {
      const u16* wg_t = w_t + ((size_t)g << 20) + kcol;
#pragma unroll
      for (int j = 0; j < 2; ++j) {
        int c = (j << 2) | wid;
        stage_chunk(wg_t + ((size_t)c << 13), &lds[W_U(g) + c * 512]);
      }
    }
    __syncthreads();  // compiler drains vmcnt(0) before barrier -> LDS ready

#pragma unroll
    for (int ks = 0; ks < 2; ++ks) {
      bf16x8 afi[4], afh[4];
#pragma unroll
      for (int i = 0; i < 4; ++i) {
        int Rm = (wm << 6) + (i << 4) + r15;
        int sl = ((ks << 2) | kb) ^ (Rm & 7);
        afi[i] = ld8(&lds[A_IN_U + Rm * 64 + sl * 8]);
        afh[i] = ld8(&lds[A_H_U  + Rm * 64 + sl * 8]);
      }
#pragma unroll
      for (int jf = 0; jf < 2; ++jf) {
        int Rn = (wn << 5) + (jf << 4) + r15;
        int sl = ((ks << 2) | kb) ^ (Rn & 7);
        bf16x8 bir = ld8(&lds[W_U(0) + Rn * 64 + sl * 8]);
        bf16x8 bhr = ld8(&lds[W_U(1) + Rn * 64 + sl * 8]);
        bf16x8 biz = ld8(&lds[W_U(2) + Rn * 64 + sl * 8]);
        bf16x8 bhz = ld8(&lds[W_U(3) + Rn * 64 + sl * 8]);
        bf16x8 bin = ld8(&lds[W_U(4) + Rn * 64 + sl * 8]);
        bf16x8 bhn = ld8(&lds[W_U(5) + Rn * 64 + sl * 8]);
#pragma unroll
        for (int i = 0; i < 4; ++i) {
          acc_r[i][jf]  = mfma16(afi[i], bir, acc_r[i][jf]);
          acc_r[i][jf]  = mfma16(afh[i], bhr, acc_r[i][jf]);
          acc_z[i][jf]  = mfma16(afi[i], biz, acc_z[i][jf]);
          acc_z[i][jf]  = mfma16(afh[i], bhz, acc_z[i][jf]);
          acc_n[i][jf]  = mfma16(afi[i], bin, acc_n[i][jf]);
          acc_hn[i][jf] = mfma16(afh[i], bhn, acc_hn[i][jf]);
        }
      }
    }
  }

  // ---- fused epilogue: gates + residual + dual store ----
  // C/D layout (m89-verified): col = lane&15, row = (lane>>4)*4 + reg
#pragma unroll
  for (int jf = 0; jf < 2; ++jf) {
    int col = (nb << 6) + (wn << 5) + (jf << 4) + r15;
    float brc = b_ir[col] + b_hr[col];
    float bzc = b_iz[col] + b_hz[col];
    float bnc = b_in[col];
    float bhc = b_hn[col];
#pragma unroll
    for (int i = 0; i < 4; ++i) {
      int row0 = (mb << 7) + (wm << 6) + (i << 4) + (kb << 2);
#pragma unroll
      for (int q = 0; q < 4; ++q) {
        int row = row0 + q;
        float vr = acc_r[i][jf][q] + brc;
        float vz = acc_z[i][jf][q] + bzc;
        float vn = acc_n[i][jf][q] + bnc;
        float vh = acc_hn[i][jf][q] + bhc;
        float rg = __builtin_amdgcn_rcpf(1.f + __expf(-vr));
        float zg = __builtin_amdgcn_rcpf(1.f + __expf(-vz));
        float pre = vn + rg * vh;
        float ax = fabsf(pre);
        float e2 = __expf(-2.f * ax);
        float th = copysignf((1.f - e2) * __builtin_amdgcn_rcpf(1.f + e2), pre);
        float hp = hidf[((size_t)row << 10) + col];
        float h = (1.f - zg) * th + zg * hp;
        size_t o = ((size_t)row << 10) + col;
        out[o] = h;
        out[o + (size_t)BATCH * DD] = h;  // tuple (h, h)
      }
    }
  }
}

extern "C" void kernel_launch(void* const* d_in, const int* in_sizes, int n_in,
                              void* d_out, int out_size, void* d_ws, size_t ws_size,
                              hipStream_t stream) {
  (void)in_sizes; (void)n_in; (void)out_size; (void)ws_size;
  const float* inp = (const float*)d_in[0];
  const float* hid = (const float*)d_in[1];
  // ws: [input bf16 64MB][hidden bf16 64MB][W_ir..W_hn bf16 12MB] = 140MB
  u16* ws_in  = (u16*)d_ws;
  u16* ws_hid = ws_in + (size_t)BATCH * DD;
  u16* ws_w   = ws_hid + (size_t)BATCH * DD;

  int n4a = BATCH * DD / 4;
  hipLaunchKernelGGL(cvt_f32_to_bf16, dim3(4096), dim3(256), 0, stream,
                     (const float4*)inp, (ushort4*)ws_in, n4a);
  hipLaunchKernelGGL(cvt_f32_to_bf16, dim3(4096), dim3(256), 0, stream,
                     (const float4*)hid, (ushort4*)ws_hid, n4a);
  for (int g = 0; g < 6; ++g) {
    hipLaunchKernelGGL(cvt_f32_to_bf16, dim3(512), dim3(256), 0, stream,
                       (const float4*)d_in[2 + 2 * g],
                       (ushort4*)(ws_w + (size_t)g * DD * DD), DD * DD / 4);
  }
  hipLaunchKernelGGL(gru_fused, dim3(4096), dim3(256), 0, stream,
                     ws_in, ws_hid, ws_w, hid,
                     (const float*)d_in[3], (const float*)d_in[5],
                     (const float*)d_in[7], (const float*)d_in[9],
                     (const float*)d_in[11], (const float*)d_in[13],
                     (float*)d_out);
}